// Round 12
// baseline (168.109 us; speedup 1.0000x reference)
//
#include <hip/hip_runtime.h>

// GAT (heads=1) + mean-pool + FC, fully collapsed.
//   out = relu((px @ W * 1/N + b_gat) @ W_fc + b_fc),  where
//   px[k] = sum_e ex_e*rden[dst_e]*x[src_e][k] + sum_n ex_self_n*rden[n]*x[n][k]
//   rden[d] = 1/(sum_{e: dst=d} ex_e + ex_self_d + 1e-16)
// c[n] is never materialized: the src-side scatter is a pure 5-wide reduction
// over edges (k_pxe). Only denom needs a segmented sum -> dst-range counting
// sort (count -> scan -> scatter records -> LDS hist -> reduce), since
// device-scope scattered atomics cap at ~19 G/s (measured r3) and multi-range
// rescanning costs R*E touches (measured r6). Self loops folded analytically.
// segment_max skipped: alpha invariant to max-shift; |e| is O(10).

#define NR 25
#define RSHIFT 12
#define RSZ 4096  // NR*RSZ = 102400 >= N ; 16 KB LDS per hist block
#define RMASK 4095
#define BBIN 256
#define BINTHR 1024
#define T 8  // hist blocks per range
#define PXE_BLOCKS 512

// ---- a_s = (x@W).att_src ; a_d = (x@W).att_dst (h never stored) ----
__global__ __launch_bounds__(256) void k_att(
    const float* __restrict__ x, const float* __restrict__ W,
    const float* __restrict__ att_src, const float* __restrict__ att_dst,
    float* __restrict__ a_s, float* __restrict__ a_d, int N) {
  const int lane = threadIdx.x & 63;
  const int n = blockIdx.x * 4 + (threadIdx.x >> 6);
  if (n >= N) return;
  const float x0 = x[n * 5 + 0], x1 = x[n * 5 + 1], x2 = x[n * 5 + 2],
              x3 = x[n * 5 + 3], x4 = x[n * 5 + 4];
  float hv = x0 * W[0 * 64 + lane];
  hv += x1 * W[1 * 64 + lane];
  hv += x2 * W[2 * 64 + lane];
  hv += x3 * W[3 * 64 + lane];
  hv += x4 * W[4 * 64 + lane];
  float t1 = hv * att_src[lane];
  float t2 = hv * att_dst[lane];
#pragma unroll
  for (int o = 32; o > 0; o >>= 1) {
    t1 += __shfl_xor(t1, o, 64);
    t2 += __shfl_xor(t2, o, 64);
  }
  if (lane == 0) {
    a_s[n] = t1;
    a_d[n] = t2;
  }
}

// ---- per-(range, block) dst counts ----
__global__ __launch_bounds__(BINTHR) void k_cnt(const int* __restrict__ ei,
                                                int* __restrict__ counts,
                                                int E) {
  __shared__ int cd[NR];
  if (threadIdx.x < NR) cd[threadIdx.x] = 0;
  __syncthreads();
  const int chunk = (E + BBIN - 1) / BBIN;
  const int lo = blockIdx.x * chunk;
  const int hi = (lo + chunk < E) ? lo + chunk : E;
#pragma unroll 4
  for (int j = lo + threadIdx.x; j < hi; j += BINTHR)
    atomicAdd(&cd[ei[E + j] >> RSHIFT], 1);
  __syncthreads();
  if (threadIdx.x < NR)
    counts[threadIdx.x * BBIN + blockIdx.x] = cd[threadIdx.x];
}

// ---- exact exclusive offsets; rinfo = [base | tot] ----
__global__ __launch_bounds__(BINTHR) void k_scan1(const int* __restrict__ counts,
                                                  int* __restrict__ offs,
                                                  int* __restrict__ rinfo) {
  __shared__ int lc[NR * BBIN];  // 25.6 KB
  __shared__ int tot[NR], base[NR];
  for (int i = threadIdx.x; i < NR * BBIN; i += BINTHR) lc[i] = counts[i];
  __syncthreads();
  if (threadIdx.x < NR) {
    int s = 0;
    const int* row = &lc[threadIdx.x * BBIN];
    for (int b = 0; b < BBIN; ++b) s += row[b];
    tot[threadIdx.x] = s;
  }
  __syncthreads();
  if (threadIdx.x == 0) {
    int a = 0;
    for (int r = 0; r < NR; ++r) {
      base[r] = a;
      a += tot[r];
    }
  }
  __syncthreads();
  if (threadIdx.x < NR) {
    int run = base[threadIdx.x];
    int* orow = &offs[threadIdx.x * BBIN];
    const int* row = &lc[threadIdx.x * BBIN];
    for (int b = 0; b < BBIN; ++b) {
      orow[b] = run;
      run += row[b];
    }
    rinfo[threadIdx.x] = base[threadIdx.x];
    rinfo[NR + threadIdx.x] = tot[threadIdx.x];
  }
}

// ---- scatter: ex computed once, record (ki_dst, ex) at exact slot ----
__global__ __launch_bounds__(BINTHR) void k_scat(
    const int* __restrict__ ei, const float* __restrict__ a_s,
    const float* __restrict__ a_d, const int* __restrict__ offs,
    uint2* __restrict__ rec, int E) {
  __shared__ int cur[NR];
  if (threadIdx.x < NR)
    cur[threadIdx.x] = offs[threadIdx.x * BBIN + blockIdx.x];
  __syncthreads();
  const int chunk = (E + BBIN - 1) / BBIN;
  const int lo = blockIdx.x * chunk;
  const int hi = (lo + chunk < E) ? lo + chunk : E;
#pragma unroll 2
  for (int j = lo + threadIdx.x; j < hi; j += BINTHR) {
    const int s = ei[j];
    const int d = ei[E + j];
    float e = a_s[s] + a_d[d];
    e = e > 0.f ? e : 0.2f * e;
    const float ex = __expf(e);
    const int slot = atomicAdd(&cur[d >> RSHIFT], 1);
    rec[slot] = make_uint2((unsigned)(d & RMASK), __float_as_uint(ex));
  }
}

// ---- LDS histogram over this range's contiguous records ----
__global__ __launch_bounds__(256) void k_hist(const uint2* __restrict__ rec,
                                              const int* __restrict__ rinfo,
                                              float* __restrict__ slab) {
  __shared__ float hist[RSZ];
  const int r = blockIdx.x / T;
  const int t = blockIdx.x % T;
  for (int i = threadIdx.x; i < RSZ; i += 256) hist[i] = 0.f;
  __syncthreads();
  const int base = rinfo[r];
  const int tot = rinfo[NR + r];
  const int L = (tot + T - 1) / T;
  const int lo = base + t * L;
  const int hh = (t + 1) * L < tot ? (t + 1) * L : tot;
  const int hi = base + hh;
#pragma unroll 4
  for (int j = lo + threadIdx.x; j < hi; j += 256) {
    const uint2 rv = rec[j];
    atomicAdd(&hist[rv.x], __uint_as_float(rv.y));
  }
  __syncthreads();
  float* outp = slab + ((size_t)(r * T + t)) * RSZ;
  for (int i = threadIdx.x; i < RSZ; i += 256) outp[i] = hist[i];
}

// ---- rden[n] = 1/(sum_T slabs + ex_self + eps) ----
__global__ __launch_bounds__(256) void k_rden(const float* __restrict__ slab,
                                              const float* __restrict__ a_s,
                                              const float* __restrict__ a_d,
                                              float* __restrict__ rden, int N) {
  const int n = blockIdx.x * 256 + threadIdx.x;
  if (n >= N) return;
  const int g = n >> RSHIFT;
  const int i = n & RMASK;
  const float* sp = slab + (size_t)g * T * RSZ + i;
  float sum = 0.f;
#pragma unroll
  for (int t = 0; t < T; ++t) sum += sp[(size_t)t * RSZ];
  float e = a_s[n] + a_d[n];
  e = e > 0.f ? e : 0.2f * e;
  rden[n] = 1.0f / (sum + __expf(e) + 1e-16f);
}

// ---- px[k] partials: reduce over edges (+ self loops), no scatter ----
__global__ __launch_bounds__(256) void k_pxe(
    const int* __restrict__ ei, const float* __restrict__ a_s,
    const float* __restrict__ a_d, const float* __restrict__ rden,
    const float* __restrict__ x, float* __restrict__ partial, int E, int N) {
  float a0 = 0.f, a1 = 0.f, a2 = 0.f, a3 = 0.f, a4 = 0.f;
  for (int j = blockIdx.x * 256 + threadIdx.x; j < E; j += gridDim.x * 256) {
    const int s = ei[j];
    const int d = ei[E + j];
    float e = a_s[s] + a_d[d];
    e = e > 0.f ? e : 0.2f * e;
    const float w = __expf(e) * rden[d];
    const float* xp = x + (size_t)s * 5;
    a0 += w * xp[0];
    a1 += w * xp[1];
    a2 += w * xp[2];
    a3 += w * xp[3];
    a4 += w * xp[4];
  }
  // self loops (coalesced)
  for (int n = blockIdx.x * 256 + threadIdx.x; n < N; n += gridDim.x * 256) {
    float e = a_s[n] + a_d[n];
    e = e > 0.f ? e : 0.2f * e;
    const float w = __expf(e) * rden[n];
    const float* xp = x + (size_t)n * 5;
    a0 += w * xp[0];
    a1 += w * xp[1];
    a2 += w * xp[2];
    a3 += w * xp[3];
    a4 += w * xp[4];
  }
#pragma unroll
  for (int o = 32; o > 0; o >>= 1) {
    a0 += __shfl_xor(a0, o, 64);
    a1 += __shfl_xor(a1, o, 64);
    a2 += __shfl_xor(a2, o, 64);
    a3 += __shfl_xor(a3, o, 64);
    a4 += __shfl_xor(a4, o, 64);
  }
  __shared__ float s5[4][5];
  const int lane = threadIdx.x & 63;
  const int w = threadIdx.x >> 6;
  if (lane == 0) {
    s5[w][0] = a0;
    s5[w][1] = a1;
    s5[w][2] = a2;
    s5[w][3] = a3;
    s5[w][4] = a4;
  }
  __syncthreads();
  if (threadIdx.x < 5)
    partial[blockIdx.x * 5 + threadIdx.x] =
        s5[0][threadIdx.x] + s5[1][threadIdx.x] + s5[2][threadIdx.x] +
        s5[3][threadIdx.x];
}

// ---- reduce partials, pooled = px@W*invN + b_gat, FC 64->72 + relu ----
__global__ __launch_bounds__(256) void k_fin(
    const float* __restrict__ partial, const float* __restrict__ W,
    const float* __restrict__ b_gat, const float* __restrict__ W_fc,
    const float* __restrict__ b_fc, float* __restrict__ out, float invN) {
  __shared__ float pp[PXE_BLOCKS * 5];  // 10 KB
  __shared__ float px[5];
  __shared__ float pooled[64];
  const int t = threadIdx.x;
  for (int i = t; i < PXE_BLOCKS * 5; i += 256) pp[i] = partial[i];
  __syncthreads();
  if (t < 5) {
    float s = 0.f;
    for (int b = 0; b < PXE_BLOCKS; ++b) s += pp[b * 5 + t];
    px[t] = s * invN;
  }
  __syncthreads();
  if (t < 64) {
    float s = b_gat[t];
#pragma unroll
    for (int k = 0; k < 5; ++k) s += px[k] * W[k * 64 + t];
    pooled[t] = s;
  }
  __syncthreads();
  if (t < 72) {
    float s = b_fc[t];
#pragma unroll
    for (int f = 0; f < 64; ++f) s += pooled[f] * W_fc[f * 72 + t];
    out[t] = s > 0.f ? s : 0.f;
  }
}

extern "C" void kernel_launch(void* const* d_in, const int* in_sizes, int n_in,
                              void* d_out, int out_size, void* d_ws,
                              size_t ws_size, hipStream_t stream) {
  const float* x = (const float*)d_in[0];
  const int* ei = (const int*)d_in[1];
  const float* W = (const float*)d_in[2];
  const float* att_src = (const float*)d_in[3];
  const float* att_dst = (const float*)d_in[4];
  const float* b_gat = (const float*)d_in[5];
  const float* W_fc = (const float*)d_in[6];
  const float* b_fc = (const float*)d_in[7];
  float* out = (float*)d_out;

  const int N = in_sizes[0] / 5;  // 100000
  const int E = in_sizes[1] / 2;  // 1600000

  char* p = (char*)d_ws;
  auto alloc = [&](size_t nbytes) -> void* {
    void* r = (void*)p;
    p += (nbytes + 255) & ~(size_t)255;
    return r;
  };
  float* a_s = (float*)alloc((size_t)N * sizeof(float));
  float* a_d = (float*)alloc((size_t)N * sizeof(float));
  float* rden = (float*)alloc((size_t)N * sizeof(float));
  int* counts = (int*)alloc((size_t)NR * BBIN * sizeof(int));
  int* offs = (int*)alloc((size_t)NR * BBIN * sizeof(int));
  int* rinfo = (int*)alloc((size_t)2 * NR * sizeof(int));
  uint2* rec = (uint2*)alloc((size_t)E * sizeof(uint2));             // 12.8 MB
  float* slab = (float*)alloc((size_t)NR * T * RSZ * sizeof(float)); // 3.3 MB
  float* partial = (float*)alloc((size_t)PXE_BLOCKS * 5 * sizeof(float));

  k_att<<<(N + 3) / 4, 256, 0, stream>>>(x, W, att_src, att_dst, a_s, a_d, N);
  k_cnt<<<BBIN, BINTHR, 0, stream>>>(ei, counts, E);
  k_scan1<<<1, BINTHR, 0, stream>>>(counts, offs, rinfo);
  k_scat<<<BBIN, BINTHR, 0, stream>>>(ei, a_s, a_d, offs, rec, E);
  k_hist<<<NR * T, 256, 0, stream>>>(rec, rinfo, slab);
  k_rden<<<(N + 255) / 256, 256, 0, stream>>>(slab, a_s, a_d, rden, N);
  k_pxe<<<PXE_BLOCKS, 256, 0, stream>>>(ei, a_s, a_d, rden, x, partial, E, N);
  k_fin<<<1, 256, 0, stream>>>(partial, W, b_gat, W_fc, b_fc, out,
                               1.0f / (float)N);
}

// Round 14
// 165.955 us; speedup vs baseline: 1.0130x; 1.0130x over previous
//
#include <hip/hip_runtime.h>

// GAT (heads=1) + mean-pool + FC, fully collapsed.
//   out = relu((px @ W * 1/N + b_gat) @ W_fc + b_fc)
//   px[k] = sum_d [ V_d[k] + ex_self_d*x[d][k] ] * rden[d]   (via dst-binned recs)
//   rden[d] = 1/(sum_{e: dst=d} ex_e + ex_self_d + 1e-16)
// Edges are dst-range counting-sorted ONCE (count -> scan -> scatter 16B recs
// carrying (ki_dst, ex, src)); the LDS histogram gives denom; a second pass
// over the SAME recs applies rden from an LDS-staged range slice and gathers
// x[src] (the only scattered access left, 1 sector/edge). Self loops are
// folded analytically into the rden pass. Scattered device atomics cap at
// ~19 G/s (r3) and R-fold rescans cost R*E touches (r6) -> this structure.
// segment_max skipped: alpha invariant to max-shift; |e| is O(10).

#define NR 25
#define RSHIFT 12
#define RSZ 4096  // NR*RSZ = 102400 >= N ; 16 KB LDS slice
#define RMASK 4095
#define BBIN 256     // cnt/scat blocks
#define SCTHR 1024   // scat threads
#define T 8          // hist blocks per range
#define HTHR 512
#define TP 16        // pxr blocks per range
#define PTHR 512
#define MAXPART 1024

// ---- fused: att blocks compute a_s/a_d; cnt blocks count dst ranges ----
__global__ __launch_bounds__(256) void k_attcnt(
    const float* __restrict__ x, const float* __restrict__ W,
    const float* __restrict__ att_src, const float* __restrict__ att_dst,
    float* __restrict__ a_s, float* __restrict__ a_d,
    const int* __restrict__ ei, int* __restrict__ counts, int N, int E,
    int NA) {
  __shared__ int cd[NR];
  if ((int)blockIdx.x < NA) {
    const int lane = threadIdx.x & 63;
    const int n = blockIdx.x * 4 + (threadIdx.x >> 6);
    if (n >= N) return;
    const float x0 = x[n * 5 + 0], x1 = x[n * 5 + 1], x2 = x[n * 5 + 2],
                x3 = x[n * 5 + 3], x4 = x[n * 5 + 4];
    float hv = x0 * W[0 * 64 + lane];
    hv += x1 * W[1 * 64 + lane];
    hv += x2 * W[2 * 64 + lane];
    hv += x3 * W[3 * 64 + lane];
    hv += x4 * W[4 * 64 + lane];
    float t1 = hv * att_src[lane];
    float t2 = hv * att_dst[lane];
#pragma unroll
    for (int o = 32; o > 0; o >>= 1) {
      t1 += __shfl_xor(t1, o, 64);
      t2 += __shfl_xor(t2, o, 64);
    }
    if (lane == 0) {
      a_s[n] = t1;
      a_d[n] = t2;
    }
  } else {
    const int b = blockIdx.x - NA;  // 0..BBIN-1
    if (threadIdx.x < NR) cd[threadIdx.x] = 0;
    __syncthreads();
    const int chunk = (E + BBIN - 1) / BBIN;
    const int lo = b * chunk;
    const int hi = (lo + chunk < E) ? lo + chunk : E;
#pragma unroll 4
    for (int j = lo + threadIdx.x; j < hi; j += 256)
      atomicAdd(&cd[ei[E + j] >> RSHIFT], 1);
    __syncthreads();
    if (threadIdx.x < NR) counts[threadIdx.x * BBIN + b] = cd[threadIdx.x];
  }
}

// ---- exact exclusive offsets; rinfo = [base | tot] ----
__global__ __launch_bounds__(1024) void k_scan1(const int* __restrict__ counts,
                                                int* __restrict__ offs,
                                                int* __restrict__ rinfo) {
  __shared__ int lc[NR * BBIN];  // 25.6 KB
  __shared__ int tot[NR], base[NR];
  for (int i = threadIdx.x; i < NR * BBIN; i += 1024) lc[i] = counts[i];
  __syncthreads();
  if (threadIdx.x < NR) {
    int s = 0;
    const int* row = &lc[threadIdx.x * BBIN];
    for (int b = 0; b < BBIN; ++b) s += row[b];
    tot[threadIdx.x] = s;
  }
  __syncthreads();
  if (threadIdx.x == 0) {
    int a = 0;
    for (int r = 0; r < NR; ++r) {
      base[r] = a;
      a += tot[r];
    }
  }
  __syncthreads();
  if (threadIdx.x < NR) {
    int run = base[threadIdx.x];
    int* orow = &offs[threadIdx.x * BBIN];
    const int* row = &lc[threadIdx.x * BBIN];
    for (int b = 0; b < BBIN; ++b) {
      orow[b] = run;
      run += row[b];
    }
    rinfo[threadIdx.x] = base[threadIdx.x];
    rinfo[NR + threadIdx.x] = tot[threadIdx.x];
  }
}

// ---- scatter: rec = (ki_dst, ex_bits, src, 0) at exact slot ----
__global__ __launch_bounds__(SCTHR) void k_scat(
    const int* __restrict__ ei, const float* __restrict__ a_s,
    const float* __restrict__ a_d, const int* __restrict__ offs,
    uint4* __restrict__ rec, int E) {
  __shared__ int cur[NR];
  if (threadIdx.x < NR)
    cur[threadIdx.x] = offs[threadIdx.x * BBIN + blockIdx.x];
  __syncthreads();
  const int chunk = (E + BBIN - 1) / BBIN;
  const int lo = blockIdx.x * chunk;
  const int hi = (lo + chunk < E) ? lo + chunk : E;
#pragma unroll 2
  for (int j = lo + threadIdx.x; j < hi; j += SCTHR) {
    const int s = ei[j];
    const int d = ei[E + j];
    float e = a_s[s] + a_d[d];
    e = e > 0.f ? e : 0.2f * e;
    const float ex = __expf(e);
    const int slot = atomicAdd(&cur[d >> RSHIFT], 1);
    rec[slot] = make_uint4((unsigned)(d & RMASK), __float_as_uint(ex),
                           (unsigned)s, 0u);
  }
}

// ---- LDS histogram (denominator) over this range's contiguous records ----
__global__ __launch_bounds__(HTHR) void k_hist(const uint4* __restrict__ rec,
                                               const int* __restrict__ rinfo,
                                               float* __restrict__ slab) {
  __shared__ float hist[RSZ];
  const int r = blockIdx.x / T;
  const int t = blockIdx.x % T;
  for (int i = threadIdx.x; i < RSZ; i += HTHR) hist[i] = 0.f;
  __syncthreads();
  const int base = rinfo[r];
  const int tot = rinfo[NR + r];
  const int L = (tot + T - 1) / T;
  const int lo = base + t * L;
  const int hh = (t + 1) * L < tot ? (t + 1) * L : tot;
  const int hi = base + hh;
#pragma unroll 4
  for (int j = lo + threadIdx.x; j < hi; j += HTHR) {
    const uint4 rv = rec[j];
    atomicAdd(&hist[rv.x], __uint_as_float(rv.y));
  }
  __syncthreads();
  float* outp = slab + ((size_t)(r * T + t)) * RSZ;
  for (int i = threadIdx.x; i < RSZ; i += HTHR) outp[i] = hist[i];
}

// ---- rden[n] = 1/(sum+ex_self+eps); also self-loop px partial ----
__global__ __launch_bounds__(256) void k_rdenpx(
    const float* __restrict__ slab, const float* __restrict__ a_s,
    const float* __restrict__ a_d, const float* __restrict__ x,
    float* __restrict__ rden, float* __restrict__ partial, int N, int pbase) {
  const int n = blockIdx.x * 256 + threadIdx.x;
  float a0 = 0.f, a1 = 0.f, a2 = 0.f, a3 = 0.f, a4 = 0.f;
  if (n < N) {
    const int g = n >> RSHIFT;
    const int i = n & RMASK;
    const float* sp = slab + (size_t)g * T * RSZ + i;
    float sum = 0.f;
#pragma unroll
    for (int t = 0; t < T; ++t) sum += sp[(size_t)t * RSZ];
    float e = a_s[n] + a_d[n];
    e = e > 0.f ? e : 0.2f * e;
    const float exs = __expf(e);
    const float r = 1.0f / (sum + exs + 1e-16f);
    rden[n] = r;
    const float w = exs * r;
    const float* xp = x + (size_t)n * 5;
    a0 = w * xp[0];
    a1 = w * xp[1];
    a2 = w * xp[2];
    a3 = w * xp[3];
    a4 = w * xp[4];
  }
#pragma unroll
  for (int o = 32; o > 0; o >>= 1) {
    a0 += __shfl_xor(a0, o, 64);
    a1 += __shfl_xor(a1, o, 64);
    a2 += __shfl_xor(a2, o, 64);
    a3 += __shfl_xor(a3, o, 64);
    a4 += __shfl_xor(a4, o, 64);
  }
  __shared__ float s5[4][5];
  const int lane = threadIdx.x & 63;
  const int w = threadIdx.x >> 6;
  if (lane == 0) {
    s5[w][0] = a0;
    s5[w][1] = a1;
    s5[w][2] = a2;
    s5[w][3] = a3;
    s5[w][4] = a4;
  }
  __syncthreads();
  if (threadIdx.x < 5)
    partial[(size_t)(pbase + blockIdx.x) * 5 + threadIdx.x] =
        s5[0][threadIdx.x] + s5[1][threadIdx.x] + s5[2][threadIdx.x] +
        s5[3][threadIdx.x];
}

// ---- px partials over records: w = ex * rden_lds[ki]; gather x[src] ----
__global__ __launch_bounds__(PTHR) void k_pxr(const uint4* __restrict__ rec,
                                              const int* __restrict__ rinfo,
                                              const float* __restrict__ rden,
                                              const float* __restrict__ x,
                                              float* __restrict__ partial,
                                              int N) {
  __shared__ float rlds[RSZ];  // 16 KB range slice of rden
  const int r = blockIdx.x / TP;
  const int t = blockIdx.x % TP;
  const int gbase = r * RSZ;
  for (int i = threadIdx.x; i < RSZ; i += PTHR) {
    const int gi = gbase + i;
    rlds[i] = (gi < N) ? rden[gi] : 0.f;
  }
  __syncthreads();
  const int base = rinfo[r];
  const int tot = rinfo[NR + r];
  const int L = (tot + TP - 1) / TP;
  const int lo = base + t * L;
  const int hh = (t + 1) * L < tot ? (t + 1) * L : tot;
  const int hi = base + hh;
  float a0 = 0.f, a1 = 0.f, a2 = 0.f, a3 = 0.f, a4 = 0.f;
#pragma unroll 2
  for (int j = lo + threadIdx.x; j < hi; j += PTHR) {
    const uint4 rv = rec[j];
    const float w = __uint_as_float(rv.y) * rlds[rv.x];
    const float* xp = x + (size_t)rv.z * 5;
    a0 += w * xp[0];
    a1 += w * xp[1];
    a2 += w * xp[2];
    a3 += w * xp[3];
    a4 += w * xp[4];
  }
#pragma unroll
  for (int o = 32; o > 0; o >>= 1) {
    a0 += __shfl_xor(a0, o, 64);
    a1 += __shfl_xor(a1, o, 64);
    a2 += __shfl_xor(a2, o, 64);
    a3 += __shfl_xor(a3, o, 64);
    a4 += __shfl_xor(a4, o, 64);
  }
  __shared__ float s5[PTHR / 64][5];
  const int lane = threadIdx.x & 63;
  const int w = threadIdx.x >> 6;
  if (lane == 0) {
    s5[w][0] = a0;
    s5[w][1] = a1;
    s5[w][2] = a2;
    s5[w][3] = a3;
    s5[w][4] = a4;
  }
  __syncthreads();
  if (threadIdx.x < 5) {
    float s = 0.f;
#pragma unroll
    for (int ww = 0; ww < PTHR / 64; ++ww) s += s5[ww][threadIdx.x];
    partial[(size_t)blockIdx.x * 5 + threadIdx.x] = s;
  }
}

// ---- reduce partials, pooled = px@W*invN + b_gat, FC 64->72 + relu ----
__global__ __launch_bounds__(256) void k_fin(
    const float* __restrict__ partial, int nparts, const float* __restrict__ W,
    const float* __restrict__ b_gat, const float* __restrict__ W_fc,
    const float* __restrict__ b_fc, float* __restrict__ out, float invN) {
  __shared__ float pp[MAXPART * 5];  // 20 KB
  __shared__ float px[5];
  __shared__ float pooled[64];
  const int t = threadIdx.x;
  for (int i = t; i < nparts * 5; i += 256) pp[i] = partial[i];
  __syncthreads();
  if (t < 5) {
    float s = 0.f;
    for (int b = 0; b < nparts; ++b) s += pp[b * 5 + t];
    px[t] = s * invN;
  }
  __syncthreads();
  if (t < 64) {
    float s = b_gat[t];
#pragma unroll
    for (int k = 0; k < 5; ++k) s += px[k] * W[k * 64 + t];
    pooled[t] = s;
  }
  __syncthreads();
  if (t < 72) {
    float s = b_fc[t];
#pragma unroll
    for (int f = 0; f < 64; ++f) s += pooled[f] * W_fc[f * 72 + t];
    out[t] = s > 0.f ? s : 0.f;
  }
}

extern "C" void kernel_launch(void* const* d_in, const int* in_sizes, int n_in,
                              void* d_out, int out_size, void* d_ws,
                              size_t ws_size, hipStream_t stream) {
  const float* x = (const float*)d_in[0];
  const int* ei = (const int*)d_in[1];
  const float* W = (const float*)d_in[2];
  const float* att_src = (const float*)d_in[3];
  const float* att_dst = (const float*)d_in[4];
  const float* b_gat = (const float*)d_in[5];
  const float* W_fc = (const float*)d_in[6];
  const float* b_fc = (const float*)d_in[7];
  float* out = (float*)d_out;

  const int N = in_sizes[0] / 5;  // 100000
  const int E = in_sizes[1] / 2;  // 1600000
  const int NA = (N + 3) / 4;     // att blocks
  const int RDB = (N + 255) / 256;
  const int nparts = NR * TP + RDB;  // 400 + 391 = 791 <= MAXPART

  char* p = (char*)d_ws;
  auto alloc = [&](size_t nbytes) -> void* {
    void* r = (void*)p;
    p += (nbytes + 255) & ~(size_t)255;
    return r;
  };
  float* a_s = (float*)alloc((size_t)N * sizeof(float));
  float* a_d = (float*)alloc((size_t)N * sizeof(float));
  float* rden = (float*)alloc((size_t)N * sizeof(float));
  int* counts = (int*)alloc((size_t)NR * BBIN * sizeof(int));
  int* offs = (int*)alloc((size_t)NR * BBIN * sizeof(int));
  int* rinfo = (int*)alloc((size_t)2 * NR * sizeof(int));
  uint4* rec = (uint4*)alloc((size_t)E * sizeof(uint4));              // 25.6 MB
  float* slab = (float*)alloc((size_t)NR * T * RSZ * sizeof(float));  // 3.3 MB
  float* partial = (float*)alloc((size_t)MAXPART * 5 * sizeof(float));

  k_attcnt<<<NA + BBIN, 256, 0, stream>>>(x, W, att_src, att_dst, a_s, a_d, ei,
                                          counts, N, E, NA);
  k_scan1<<<1, 1024, 0, stream>>>(counts, offs, rinfo);
  k_scat<<<BBIN, SCTHR, 0, stream>>>(ei, a_s, a_d, offs, rec, E);
  k_hist<<<NR * T, HTHR, 0, stream>>>(rec, rinfo, slab);
  k_rdenpx<<<RDB, 256, 0, stream>>>(slab, a_s, a_d, x, rden, partial, N,
                                    NR * TP);
  k_pxr<<<NR * TP, PTHR, 0, stream>>>(rec, rinfo, rden, x, partial, N);
  k_fin<<<1, 256, 0, stream>>>(partial, nparts, W, b_gat, W_fc, b_fc, out,
                               1.0f / (float)N);
}

// Round 15
// 161.824 us; speedup vs baseline: 1.0388x; 1.0255x over previous
//
#include <hip/hip_runtime.h>

// GAT (heads=1) + mean-pool + FC, fully collapsed.
//   out = relu((px @ W * 1/N + b_gat) @ W_fc + b_fc)
//   px[k] = sum_recs ex*rden[dst]*x[src][k] + sum_n ex_self_n*rden[n]*x[n][k]
//   rden[d] = 1/(sum_{e: dst=d} ex_e + ex_self_d + 1e-16)
// Edges are dst-range counting-sorted ONCE (count -> scan -> scatter 8B recs:
// word0 = src<<12 | ki_dst (src<2^17, ki<2^12 -> 29 bits), word1 = ex bits).
// LDS histogram gives denom; a second pass over the SAME recs applies rden
// from an LDS-staged range slice and gathers x[src] (1 scattered access/edge,
// L2-resident). Self loops folded analytically into the rden pass.
// Scattered device atomics cap ~19 G/s (r3); R-fold rescans cost R*E (r6).
// segment_max skipped: alpha invariant to max-shift; |e| is O(10).

#define NR 25
#define RSHIFT 12
#define RSZ 4096  // NR*RSZ = 102400 >= N ; 16 KB LDS slice
#define RMASK 4095
#define BBIN 256     // cnt/scat blocks
#define SCTHR 1024   // scat threads
#define T 8          // hist blocks per range
#define HTHR 512
#define TP 16        // pxr blocks per range
#define PTHR 512
#define MAXPART 1024

// ---- fused: att blocks compute a_s/a_d; cnt blocks count dst ranges ----
__global__ __launch_bounds__(256) void k_attcnt(
    const float* __restrict__ x, const float* __restrict__ W,
    const float* __restrict__ att_src, const float* __restrict__ att_dst,
    float* __restrict__ a_s, float* __restrict__ a_d,
    const int* __restrict__ ei, int* __restrict__ counts, int N, int E,
    int NA) {
  __shared__ int cd[NR];
  if ((int)blockIdx.x < NA) {
    const int lane = threadIdx.x & 63;
    const int n = blockIdx.x * 4 + (threadIdx.x >> 6);
    if (n >= N) return;
    const float x0 = x[n * 5 + 0], x1 = x[n * 5 + 1], x2 = x[n * 5 + 2],
                x3 = x[n * 5 + 3], x4 = x[n * 5 + 4];
    float hv = x0 * W[0 * 64 + lane];
    hv += x1 * W[1 * 64 + lane];
    hv += x2 * W[2 * 64 + lane];
    hv += x3 * W[3 * 64 + lane];
    hv += x4 * W[4 * 64 + lane];
    float t1 = hv * att_src[lane];
    float t2 = hv * att_dst[lane];
#pragma unroll
    for (int o = 32; o > 0; o >>= 1) {
      t1 += __shfl_xor(t1, o, 64);
      t2 += __shfl_xor(t2, o, 64);
    }
    if (lane == 0) {
      a_s[n] = t1;
      a_d[n] = t2;
    }
  } else {
    const int b = blockIdx.x - NA;  // 0..BBIN-1
    if (threadIdx.x < NR) cd[threadIdx.x] = 0;
    __syncthreads();
    const int chunk = (E + BBIN - 1) / BBIN;
    const int lo = b * chunk;
    const int hi = (lo + chunk < E) ? lo + chunk : E;
#pragma unroll 4
    for (int j = lo + threadIdx.x; j < hi; j += 256)
      atomicAdd(&cd[ei[E + j] >> RSHIFT], 1);
    __syncthreads();
    if (threadIdx.x < NR) counts[threadIdx.x * BBIN + b] = cd[threadIdx.x];
  }
}

// ---- exact exclusive offsets; rinfo = [base | tot] ----
__global__ __launch_bounds__(1024) void k_scan1(const int* __restrict__ counts,
                                                int* __restrict__ offs,
                                                int* __restrict__ rinfo) {
  __shared__ int lc[NR * BBIN];  // 25.6 KB
  __shared__ int tot[NR], base[NR];
  for (int i = threadIdx.x; i < NR * BBIN; i += 1024) lc[i] = counts[i];
  __syncthreads();
  if (threadIdx.x < NR) {
    int s = 0;
    const int* row = &lc[threadIdx.x * BBIN];
    for (int b = 0; b < BBIN; ++b) s += row[b];
    tot[threadIdx.x] = s;
  }
  __syncthreads();
  if (threadIdx.x == 0) {
    int a = 0;
    for (int r = 0; r < NR; ++r) {
      base[r] = a;
      a += tot[r];
    }
  }
  __syncthreads();
  if (threadIdx.x < NR) {
    int run = base[threadIdx.x];
    int* orow = &offs[threadIdx.x * BBIN];
    const int* row = &lc[threadIdx.x * BBIN];
    for (int b = 0; b < BBIN; ++b) {
      orow[b] = run;
      run += row[b];
    }
    rinfo[threadIdx.x] = base[threadIdx.x];
    rinfo[NR + threadIdx.x] = tot[threadIdx.x];
  }
}

// ---- scatter: rec = (src<<12 | ki_dst, ex_bits) at exact slot ----
__global__ __launch_bounds__(SCTHR) void k_scat(
    const int* __restrict__ ei, const float* __restrict__ a_s,
    const float* __restrict__ a_d, const int* __restrict__ offs,
    uint2* __restrict__ rec, int E) {
  __shared__ int cur[NR];
  if (threadIdx.x < NR)
    cur[threadIdx.x] = offs[threadIdx.x * BBIN + blockIdx.x];
  __syncthreads();
  const int chunk = (E + BBIN - 1) / BBIN;
  const int lo = blockIdx.x * chunk;
  const int hi = (lo + chunk < E) ? lo + chunk : E;
#pragma unroll 2
  for (int j = lo + threadIdx.x; j < hi; j += SCTHR) {
    const int s = ei[j];
    const int d = ei[E + j];
    float e = a_s[s] + a_d[d];
    e = e > 0.f ? e : 0.2f * e;
    const float ex = __expf(e);
    const int slot = atomicAdd(&cur[d >> RSHIFT], 1);
    rec[slot] = make_uint2(((unsigned)s << RSHIFT) | (unsigned)(d & RMASK),
                           __float_as_uint(ex));
  }
}

// ---- LDS histogram (denominator) over this range's contiguous records ----
__global__ __launch_bounds__(HTHR) void k_hist(const uint2* __restrict__ rec,
                                               const int* __restrict__ rinfo,
                                               float* __restrict__ slab) {
  __shared__ float hist[RSZ];
  const int r = blockIdx.x / T;
  const int t = blockIdx.x % T;
  for (int i = threadIdx.x; i < RSZ; i += HTHR) hist[i] = 0.f;
  __syncthreads();
  const int base = rinfo[r];
  const int tot = rinfo[NR + r];
  const int L = (tot + T - 1) / T;
  const int lo = base + t * L;
  const int hh = (t + 1) * L < tot ? (t + 1) * L : tot;
  const int hi = base + hh;
#pragma unroll 4
  for (int j = lo + threadIdx.x; j < hi; j += HTHR) {
    const uint2 rv = rec[j];
    atomicAdd(&hist[rv.x & RMASK], __uint_as_float(rv.y));
  }
  __syncthreads();
  float* outp = slab + ((size_t)(r * T + t)) * RSZ;
  for (int i = threadIdx.x; i < RSZ; i += HTHR) outp[i] = hist[i];
}

// ---- rden[n] = 1/(sum+ex_self+eps); also self-loop px partial ----
__global__ __launch_bounds__(256) void k_rdenpx(
    const float* __restrict__ slab, const float* __restrict__ a_s,
    const float* __restrict__ a_d, const float* __restrict__ x,
    float* __restrict__ rden, float* __restrict__ partial, int N, int pbase) {
  const int n = blockIdx.x * 256 + threadIdx.x;
  float a0 = 0.f, a1 = 0.f, a2 = 0.f, a3 = 0.f, a4 = 0.f;
  if (n < N) {
    const int g = n >> RSHIFT;
    const int i = n & RMASK;
    const float* sp = slab + (size_t)g * T * RSZ + i;
    float sum = 0.f;
#pragma unroll
    for (int t = 0; t < T; ++t) sum += sp[(size_t)t * RSZ];
    float e = a_s[n] + a_d[n];
    e = e > 0.f ? e : 0.2f * e;
    const float exs = __expf(e);
    const float r = 1.0f / (sum + exs + 1e-16f);
    rden[n] = r;
    const float w = exs * r;
    const float* xp = x + (size_t)n * 5;
    a0 = w * xp[0];
    a1 = w * xp[1];
    a2 = w * xp[2];
    a3 = w * xp[3];
    a4 = w * xp[4];
  }
#pragma unroll
  for (int o = 32; o > 0; o >>= 1) {
    a0 += __shfl_xor(a0, o, 64);
    a1 += __shfl_xor(a1, o, 64);
    a2 += __shfl_xor(a2, o, 64);
    a3 += __shfl_xor(a3, o, 64);
    a4 += __shfl_xor(a4, o, 64);
  }
  __shared__ float s5[4][5];
  const int lane = threadIdx.x & 63;
  const int w = threadIdx.x >> 6;
  if (lane == 0) {
    s5[w][0] = a0;
    s5[w][1] = a1;
    s5[w][2] = a2;
    s5[w][3] = a3;
    s5[w][4] = a4;
  }
  __syncthreads();
  if (threadIdx.x < 5)
    partial[(size_t)(pbase + blockIdx.x) * 5 + threadIdx.x] =
        s5[0][threadIdx.x] + s5[1][threadIdx.x] + s5[2][threadIdx.x] +
        s5[3][threadIdx.x];
}

// ---- px partials over records: w = ex * rden_lds[ki]; gather x[src] ----
__global__ __launch_bounds__(PTHR) void k_pxr(const uint2* __restrict__ rec,
                                              const int* __restrict__ rinfo,
                                              const float* __restrict__ rden,
                                              const float* __restrict__ x,
                                              float* __restrict__ partial,
                                              int N) {
  __shared__ float rlds[RSZ];  // 16 KB range slice of rden
  const int r = blockIdx.x / TP;
  const int t = blockIdx.x % TP;
  const int gbase = r * RSZ;
  for (int i = threadIdx.x; i < RSZ; i += PTHR) {
    const int gi = gbase + i;
    rlds[i] = (gi < N) ? rden[gi] : 0.f;
  }
  __syncthreads();
  const int base = rinfo[r];
  const int tot = rinfo[NR + r];
  const int L = (tot + TP - 1) / TP;
  const int lo = base + t * L;
  const int hh = (t + 1) * L < tot ? (t + 1) * L : tot;
  const int hi = base + hh;
  float a0 = 0.f, a1 = 0.f, a2 = 0.f, a3 = 0.f, a4 = 0.f;
#pragma unroll 2
  for (int j = lo + threadIdx.x; j < hi; j += PTHR) {
    const uint2 rv = rec[j];
    const float w = __uint_as_float(rv.y) * rlds[rv.x & RMASK];
    const float* xp = x + (size_t)(rv.x >> RSHIFT) * 5;
    a0 += w * xp[0];
    a1 += w * xp[1];
    a2 += w * xp[2];
    a3 += w * xp[3];
    a4 += w * xp[4];
  }
#pragma unroll
  for (int o = 32; o > 0; o >>= 1) {
    a0 += __shfl_xor(a0, o, 64);
    a1 += __shfl_xor(a1, o, 64);
    a2 += __shfl_xor(a2, o, 64);
    a3 += __shfl_xor(a3, o, 64);
    a4 += __shfl_xor(a4, o, 64);
  }
  __shared__ float s5[PTHR / 64][5];
  const int lane = threadIdx.x & 63;
  const int w = threadIdx.x >> 6;
  if (lane == 0) {
    s5[w][0] = a0;
    s5[w][1] = a1;
    s5[w][2] = a2;
    s5[w][3] = a3;
    s5[w][4] = a4;
  }
  __syncthreads();
  if (threadIdx.x < 5) {
    float s = 0.f;
#pragma unroll
    for (int ww = 0; ww < PTHR / 64; ++ww) s += s5[ww][threadIdx.x];
    partial[(size_t)blockIdx.x * 5 + threadIdx.x] = s;
  }
}

// ---- reduce partials, pooled = px@W*invN + b_gat, FC 64->72 + relu ----
__global__ __launch_bounds__(256) void k_fin(
    const float* __restrict__ partial, int nparts, const float* __restrict__ W,
    const float* __restrict__ b_gat, const float* __restrict__ W_fc,
    const float* __restrict__ b_fc, float* __restrict__ out, float invN) {
  __shared__ float pp[MAXPART * 5];  // 20 KB
  __shared__ float px[5];
  __shared__ float pooled[64];
  const int t = threadIdx.x;
  for (int i = t; i < nparts * 5; i += 256) pp[i] = partial[i];
  __syncthreads();
  if (t < 5) {
    float s = 0.f;
    for (int b = 0; b < nparts; ++b) s += pp[b * 5 + t];
    px[t] = s * invN;
  }
  __syncthreads();
  if (t < 64) {
    float s = b_gat[t];
#pragma unroll
    for (int k = 0; k < 5; ++k) s += px[k] * W[k * 64 + t];
    pooled[t] = s;
  }
  __syncthreads();
  if (t < 72) {
    float s = b_fc[t];
#pragma unroll
    for (int f = 0; f < 64; ++f) s += pooled[f] * W_fc[f * 72 + t];
    out[t] = s > 0.f ? s : 0.f;
  }
}

extern "C" void kernel_launch(void* const* d_in, const int* in_sizes, int n_in,
                              void* d_out, int out_size, void* d_ws,
                              size_t ws_size, hipStream_t stream) {
  const float* x = (const float*)d_in[0];
  const int* ei = (const int*)d_in[1];
  const float* W = (const float*)d_in[2];
  const float* att_src = (const float*)d_in[3];
  const float* att_dst = (const float*)d_in[4];
  const float* b_gat = (const float*)d_in[5];
  const float* W_fc = (const float*)d_in[6];
  const float* b_fc = (const float*)d_in[7];
  float* out = (float*)d_out;

  const int N = in_sizes[0] / 5;  // 100000
  const int E = in_sizes[1] / 2;  // 1600000
  const int NA = (N + 3) / 4;     // att blocks
  const int RDB = (N + 255) / 256;
  const int nparts = NR * TP + RDB;  // 400 + 391 = 791 <= MAXPART

  char* p = (char*)d_ws;
  auto alloc = [&](size_t nbytes) -> void* {
    void* r = (void*)p;
    p += (nbytes + 255) & ~(size_t)255;
    return r;
  };
  float* a_s = (float*)alloc((size_t)N * sizeof(float));
  float* a_d = (float*)alloc((size_t)N * sizeof(float));
  float* rden = (float*)alloc((size_t)N * sizeof(float));
  int* counts = (int*)alloc((size_t)NR * BBIN * sizeof(int));
  int* offs = (int*)alloc((size_t)NR * BBIN * sizeof(int));
  int* rinfo = (int*)alloc((size_t)2 * NR * sizeof(int));
  uint2* rec = (uint2*)alloc((size_t)E * sizeof(uint2));              // 12.8 MB
  float* slab = (float*)alloc((size_t)NR * T * RSZ * sizeof(float));  // 3.3 MB
  float* partial = (float*)alloc((size_t)MAXPART * 5 * sizeof(float));

  k_attcnt<<<NA + BBIN, 256, 0, stream>>>(x, W, att_src, att_dst, a_s, a_d, ei,
                                          counts, N, E, NA);
  k_scan1<<<1, 1024, 0, stream>>>(counts, offs, rinfo);
  k_scat<<<BBIN, SCTHR, 0, stream>>>(ei, a_s, a_d, offs, rec, E);
  k_hist<<<NR * T, HTHR, 0, stream>>>(rec, rinfo, slab);
  k_rdenpx<<<RDB, 256, 0, stream>>>(slab, a_s, a_d, x, rden, partial, N,
                                    NR * TP);
  k_pxr<<<NR * TP, PTHR, 0, stream>>>(rec, rinfo, rden, x, partial, N);
  k_fin<<<1, 256, 0, stream>>>(partial, nparts, W, b_gat, W_fc, b_fc, out,
                               1.0f / (float)N);
}